// Round 11
// baseline (1744.093 us; speedup 1.0000x reference)
//
#include <hip/hip_runtime.h>

#define T_LEN 100
#define H 32
#define L 6
#define NT 6          // 96 gate rows / 16
#define TPB 512       // 8 waves: SIMD s hosts waves {s, s+4}
#define BT 32         // two independent 16-batch groups per block
#define NPAIR 50      // two timesteps per barrier interval
#define NK (NPAIR + L - 1)   // 55 intervals, layer skew d = layer
#define S1 1.44269504088896f   // log2(e)

typedef float f32x4  __attribute__((ext_vector_type(4)));
typedef _Float16 f16x8 __attribute__((ext_vector_type(8)));

union FragU { f16x8 h; f32x4 f; unsigned int u[4]; };

__device__ inline unsigned short f2h(float f) {
    union { _Float16 h; unsigned short u; } v; v.h = (_Float16)f; return v.u;
}
__device__ inline float h2f(unsigned short u) {
    union { _Float16 h; unsigned short u; } v; v.u = u; return (float)v.h;
}
__device__ inline float rcpa(float x)  { return __builtin_amdgcn_rcpf(x); }
__device__ inline float exp2b(float x) { return __builtin_amdgcn_exp2f(x); }

// pack f32 pair -> f16 hi pair + f16 lo (residual) pair (RTZ pack; residual
// captures the truncation error, so hi+lo ~= f32 to ~2^-22)
__device__ inline void pk_pair16(float a, float b, unsigned int& hi, unsigned int& lo) {
    unsigned int h;
    asm("v_cvt_pkrtz_f16_f32 %0, %1, %2" : "=v"(h) : "v"(a), "v"(b));
    union { unsigned int u; _Float16 h2[2]; } uh; uh.u = h;
    float la = a - (float)uh.h2[0], lb = b - (float)uh.h2[1];
    unsigned int l;
    asm("v_cvt_pkrtz_f16_f32 %0, %1, %2" : "=v"(l) : "v"(la), "v"(lb));
    hi = h; lo = l;
}

// ---- prep: pack weight A-fragments as f16 (hi/lo split for W_hh, hi-only
// for W_ih), pre-scaled by -log2e / -2log2e, with kappa k-relabeling:
// hardware k-slot (gk*8+e) holds W column j = (e>>2)*16 + gk*4 + (e&3).
// This makes MFMA C/D layout == B-frag layout.
__global__ void pack_frags(const float* __restrict__ Whh, const float* __restrict__ Wih,
                           unsigned short* __restrict__ WhFhi, unsigned short* __restrict__ WhFlo,
                           unsigned short* __restrict__ WiFhi)
{
    int tid = blockIdx.x * blockDim.x + threadIdx.x;
    const int NWH = L * NT * 64;          // 2304
    const int NWI = (L - 1) * NT * 64;    // 1920
    if (tid >= NWH + NWI) return;
    const float* src; unsigned short *dhi, *dlo; int tile, lane;
    bool wantLo;
    if (tid < NWH) {
        int l = tid / (NT * 64); int r = tid % (NT * 64); tile = r / 64; lane = r % 64;
        src = Whh + l * 96 * H;
        dhi = WhFhi + tid * 8; dlo = WhFlo + tid * 8; wantLo = true;
    } else {
        int t2 = tid - NWH;
        int l = t2 / (NT * 64); int r = t2 % (NT * 64); tile = r / 64; lane = r % 64;
        src = Wih + l * 96 * H;           // W_ih[l] feeds layer l+1
        dhi = WiFhi + t2 * 8; dlo = nullptr; wantLo = false;
    }
    int row = tile * 16 + (lane & 15);
    int gk  = lane >> 4;
    float scale = (row < 64) ? -S1 : -2.0f * S1;
    unsigned short thi[8], tlo[8];
#pragma unroll
    for (int e = 0; e < 8; ++e) {
        int j = ((e >> 2) << 4) + (gk << 2) + (e & 3);   // kappa^-1
        float wv = scale * src[row * H + j];
        unsigned short h = f2h(wv);
        thi[e] = h;
        tlo[e] = f2h(wv - h2f(h));
    }
    *(uint4*)dhi = *(const uint4*)thi;
    if (wantLo) *(uint4*)dlo = *(const uint4*)tlo;
}

// ---- main: 8-wave layer ladder, barrier-synced, TWO steps per interval,
// f16: hi-only f16 inter-layer handoff (1-product input MFMA), 3-product
// f16 own-h recurrence (full precision in registers).  LDS trimmed to
// ~55 KB so TWO blocks co-reside per CU (launch_bounds min 4 waves/SIMD):
// the two blocks' independent barrier groups naturally anti-phase, filling
// each other's MFMA/gate idle cycles -- the decorrelation that scheduling
// tricks inside one barrier group could not achieve.
// VALU-balanced wave map: SIMD pairs {L0,L1a} {L2,L1b} {L3,L5a} {L4,L5b}.
__global__ __launch_bounds__(TPB, 4) void gru_mfma(
    const float* __restrict__ x,          // [B][T]
    const float* __restrict__ Wih0,       // [96]
    const float* __restrict__ bih,        // [6][96]
    const float* __restrict__ bhh,        // [6][96]
    const unsigned short* __restrict__ WhFhi, const unsigned short* __restrict__ WhFlo,
    const unsigned short* __restrict__ WiFhi,
    const float* __restrict__ Wk, const float* __restrict__ bk,
    const float* __restrict__ We, const float* __restrict__ be,
    const float* __restrict__ Wt, const float* __restrict__ bt,
    float* __restrict__ out, int B)
{
    // handoff slot per (layer 0..4, interval parity, step 0/1), 2 KB each:
    // grp0{hi 1K} grp1{hi 1K}.  row b = 64B; logical 16B-block c stored at
    // column c ^ ((b>>1)&3).
    __shared__ unsigned char slot[5][2][2][2048];   // 40 KB
    __shared__ float xt[T_LEN][BT];                 // 12.8 KB
    __shared__ float hpart[L][3][BT];               // 2.3 KB

    const int tid  = threadIdx.x;
    const int wv   = tid >> 6;        // wave index
    const int lane = tid & 63;
    const int b    = lane & 15;       // batch col (MFMA N)
    const int g    = lane >> 4;       // k-group
    const int b0   = blockIdx.x * BT;

    // wave -> (layer, group-mask).  SIMD pairs {w0,w4} {w1,w5} {w2,w6}
    // {w3,w7}; L1 and L5 split in half so every SIMD carries ~1.5 layers
    // of gate VALU/trans work:
    //   S0:{L0, L1.g0}  S1:{L2, L1.g1}  S2:{L3, L5.g0}  S3:{L4, L5.g1}
    int layer, grmask;
    switch (wv) {
      case 0: layer = 0; grmask = 3; break;   // light scalar-input layer
      case 4: layer = 1; grmask = 1; break;
      case 1: layer = 2; grmask = 3; break;
      case 5: layer = 1; grmask = 2; break;
      case 2: layer = 3; grmask = 3; break;
      case 6: layer = 5; grmask = 1; break;
      case 3: layer = 4; grmask = 3; break;
      default: layer = 5; grmask = 2; break;  // w7
    }

    // stage x tile
    for (int idx = tid; idx < T_LEN * BT; idx += TPB) {
        int bb = idx / T_LEN, t = idx % T_LEN;
        xt[t][bb] = x[(b0 + bb) * T_LEN + t];
    }

    // weight fragments for my layer, held in registers all 100 steps
    f16x8 whh[NT], whl[NT], wih[NT];
#pragma unroll
    for (int t6 = 0; t6 < NT; ++t6) {
        whh[t6] = ((const f16x8*)WhFhi)[(layer * NT + t6) * 64 + lane];
        whl[t6] = ((const f16x8*)WhFlo)[(layer * NT + t6) * 64 + lane];
    }
    if (layer > 0) {
#pragma unroll
        for (int t6 = 0; t6 < NT; ++t6)
            wih[t6] = ((const f16x8*)WiFhi)[((layer - 1) * NT + t6) * 64 + lane];
    }

    // pre-scaled biases in C/D layout (row = t6*16 + g*4 + r)
    f32x4 bc[4], bxn[2], bhn[2];
    {
        const int rb = g * 4;
#pragma unroll
        for (int t6 = 0; t6 < 4; ++t6)
#pragma unroll
            for (int r = 0; r < 4; ++r) {
                int row = t6 * 16 + rb + r;
                bc[t6][r] = -S1 * (bih[layer * 96 + row] + bhh[layer * 96 + row]);
            }
#pragma unroll
        for (int tt = 0; tt < 2; ++tt)
#pragma unroll
            for (int r = 0; r < 4; ++r) {
                int row = 64 + tt * 16 + rb + r;
                bxn[tt][r] = -2.0f * S1 * bih[layer * 96 + row];
                bhn[tt][r] = -2.0f * S1 * bhh[layer * 96 + row];
            }
        if (layer == 0) {
            // layer-0 wave never uses wih as frags: reuse for pre-scaled f32
            // input weights via the union view
#pragma unroll
            for (int t6 = 0; t6 < NT; ++t6) {
                FragU u;
#pragma unroll
                for (int r = 0; r < 4; ++r) {
                    int row = t6 * 16 + rb + r;
                    float s = (row < 64) ? -S1 : -2.0f * S1;
                    u.f[r] = s * Wih0[row];
                }
                wih[t6] = u.h;
            }
        }
    }

    float hp[2][8];
#pragma unroll
    for (int gr = 0; gr < 2; ++gr)
#pragma unroll
        for (int i = 0; i < 8; ++i) hp[gr][i] = 0.0f;
    f16x8 hfH[2] = {{0,0,0,0,0,0,0,0},{0,0,0,0,0,0,0,0}};
    f16x8 hfL[2] = {{0,0,0,0,0,0,0,0},{0,0,0,0,0,0,0,0}};

    // unified slot offset (read & write identical): row b, logical block g,
    // XOR-swizzled by (b>>1)&3.  Group gr adds gr*1024.
    const int soff = b * 64 + ((g ^ ((b >> 1) & 3)) << 4);
    unsigned char* const sbase = (unsigned char*)slot;

    // one GRU step for BOTH batch groups, batched at product level.
    // rq = producer parity to read, wp = parity to write, st = step slot.
    auto do_step2 = [&](int t, int rq, int wp, int st) {
        f32x4 acc[2][4], accX[2][2], accH[2][2];
        // both handoff LDS reads first; latency hides under own-h MFMAs
        f16x8 iH[2];
        if (layer > 0) {
            const unsigned char* ru = sbase + (((layer - 1) * 4 + rq * 2 + st) << 11);
            if (grmask & 1) iH[0] = *(const f16x8*)(ru + soff);
            if (grmask & 2) iH[1] = *(const f16x8*)(ru + 1024 + soff);
        }
        // ---- MFMA phase: product-major order; 12 independent chains ----
        // product 1: whh x hH  (C-init = biases)
#pragma unroll
        for (int gr = 0; gr < 2; ++gr)
            if (grmask & (1 << gr)) {
#pragma unroll
                for (int t6 = 0; t6 < 4; ++t6)
                    acc[gr][t6] = __builtin_amdgcn_mfma_f32_16x16x32_f16(whh[t6], hfH[gr], bc[t6], 0, 0, 0);
#pragma unroll
                for (int tt = 0; tt < 2; ++tt)
                    accH[gr][tt] = __builtin_amdgcn_mfma_f32_16x16x32_f16(whh[4 + tt], hfH[gr], bhn[tt], 0, 0, 0);
            }
        // product 2: whh x hL
#pragma unroll
        for (int gr = 0; gr < 2; ++gr)
            if (grmask & (1 << gr)) {
#pragma unroll
                for (int t6 = 0; t6 < 4; ++t6)
                    acc[gr][t6] = __builtin_amdgcn_mfma_f32_16x16x32_f16(whh[t6], hfL[gr], acc[gr][t6], 0, 0, 0);
#pragma unroll
                for (int tt = 0; tt < 2; ++tt)
                    accH[gr][tt] = __builtin_amdgcn_mfma_f32_16x16x32_f16(whh[4 + tt], hfL[gr], accH[gr][tt], 0, 0, 0);
            }
        // product 3: whl x hH
#pragma unroll
        for (int gr = 0; gr < 2; ++gr)
            if (grmask & (1 << gr)) {
#pragma unroll
                for (int t6 = 0; t6 < 4; ++t6)
                    acc[gr][t6] = __builtin_amdgcn_mfma_f32_16x16x32_f16(whl[t6], hfH[gr], acc[gr][t6], 0, 0, 0);
#pragma unroll
                for (int tt = 0; tt < 2; ++tt)
                    accH[gr][tt] = __builtin_amdgcn_mfma_f32_16x16x32_f16(whl[4 + tt], hfH[gr], accH[gr][tt], 0, 0, 0);
            }
        // input product: wih x iH (hi-only handoff) / scalar x for layer 0
        if (layer == 0) {
#pragma unroll
            for (int gr = 0; gr < 2; ++gr)
                if (grmask & (1 << gr)) {
                    float xv = xt[t][gr * 16 + b];
#pragma unroll
                    for (int t6 = 0; t6 < 4; ++t6) {
                        FragU u; u.h = wih[t6];
#pragma unroll
                        for (int r = 0; r < 4; ++r)
                            acc[gr][t6][r] = fmaf(u.f[r], xv, acc[gr][t6][r]);
                    }
#pragma unroll
                    for (int tt = 0; tt < 2; ++tt) {
                        FragU u; u.h = wih[4 + tt];
#pragma unroll
                        for (int r = 0; r < 4; ++r)
                            accX[gr][tt][r] = fmaf(u.f[r], xv, bxn[tt][r]);
                    }
                }
        } else {
#pragma unroll
            for (int gr = 0; gr < 2; ++gr)
                if (grmask & (1 << gr)) {
#pragma unroll
                    for (int t6 = 0; t6 < 4; ++t6)
                        acc[gr][t6] = __builtin_amdgcn_mfma_f32_16x16x32_f16(wih[t6], iH[gr], acc[gr][t6], 0, 0, 0);
#pragma unroll
                    for (int tt = 0; tt < 2; ++tt)
                        accX[gr][tt] = __builtin_amdgcn_mfma_f32_16x16x32_f16(wih[4 + tt], iH[gr], bxn[tt], 0, 0, 0);
                }
        }
        // ---- gate phase: both groups together (16 independent chains) ----
        // gates (pre-scaled): Er=e^-rpre, Ez=e^-zpre, En=e^-2npre
        // r = 1/(1+Er); n = (1-En)/(1+En); h = [n*Ez + hp] / (1+Ez)
#pragma unroll
        for (int gr = 0; gr < 2; ++gr)
            if (grmask & (1 << gr)) {
#pragma unroll
                for (int jj = 0; jj < 2; ++jj)
#pragma unroll
                    for (int r = 0; r < 4; ++r) {
                        float Er = exp2b(acc[gr][jj][r]);
                        float Ez = exp2b(acc[gr][2 + jj][r]);
                        float rg = rcpa(1.0f + Er);
                        float u  = fmaf(rg, accH[gr][jj][r], accX[gr][jj][r]);
                        float En = exp2b(u);
                        float en1 = 1.0f + En, ez1 = 1.0f + Ez;
                        float d   = rcpa(en1 * ez1);
                        float num = fmaf(hp[gr][jj * 4 + r], en1, (1.0f - En) * Ez);
                        hp[gr][jj * 4 + r] = num * d;
                    }
            }
        // ---- pack + handoff write, both groups ----
#pragma unroll
        for (int gr = 0; gr < 2; ++gr)
            if (grmask & (1 << gr)) {
                unsigned int h01, l01, h23, l23, h45, l45, h67, l67;
                pk_pair16(hp[gr][0], hp[gr][1], h01, l01);
                pk_pair16(hp[gr][2], hp[gr][3], h23, l23);
                pk_pair16(hp[gr][4], hp[gr][5], h45, l45);
                pk_pair16(hp[gr][6], hp[gr][7], h67, l67);
                FragU Hu, Lu;
                Hu.u[0] = h01; Hu.u[1] = h23; Hu.u[2] = h45; Hu.u[3] = h67;
                Lu.u[0] = l01; Lu.u[1] = l23; Lu.u[2] = l45; Lu.u[3] = l67;
                hfH[gr] = Hu.h; hfL[gr] = Lu.h;
                if (layer < L - 1) {
                    unsigned char* wp8 = sbase + ((layer * 4 + wp * 2 + st) << 11) + gr * 1024;
                    *(uint4*)(wp8 + soff) = make_uint4(h01, h23, h45, h67);
                }
            }
    };

    __syncthreads();

    for (int i = 0; i < NK; ++i) {
        int k = i - layer;            // local 2-step chunk index
        if (0 <= k && k < NPAIR) {
            const int p = i & 1, q = p ^ 1;
            do_step2(2 * k,     q, p, 0);
            do_step2(2 * k + 1, q, p, 1);
        }
        __syncthreads();
    }

    // heads: per-(layer,group) partial over 32 hidden units, then cross-wave reduce
    {
        const int rb = g * 4;
#pragma unroll
        for (int hd = 0; hd < 3; ++hd) {
            const float* W = (hd == 0) ? Wk : (hd == 1) ? We : Wt;
#pragma unroll
            for (int gr = 0; gr < 2; ++gr)
                if (grmask & (1 << gr)) {
                    float s = 0.0f;
#pragma unroll
                    for (int jj = 0; jj < 2; ++jj)
#pragma unroll
                        for (int r = 0; r < 4; ++r)
                            s = fmaf(W[layer * H + jj * 16 + rb + r], hp[gr][jj * 4 + r], s);
                    s += __shfl_xor(s, 16, 64);
                    s += __shfl_xor(s, 32, 64);
                    if (g == 0) hpart[layer][hd][gr * 16 + b] = s;
                }
        }
        __syncthreads();
        if (wv < 3 && lane < BT) {
            int bb = lane;
            float s = (wv == 0) ? bk[0] : (wv == 1) ? be[0] : bt[0];
#pragma unroll
            for (int l = 0; l < L; ++l) s += hpart[l][wv][bb];
            out[wv * B + b0 + bb] = s;
        }
    }
}

extern "C" void kernel_launch(void* const* d_in, const int* in_sizes, int n_in,
                              void* d_out, int out_size, void* d_ws, size_t ws_size,
                              hipStream_t stream)
{
    const float* x    = (const float*)d_in[0];
    const float* Wih0 = (const float*)d_in[1];
    const float* Wih  = (const float*)d_in[2];
    const float* Whh  = (const float*)d_in[3];
    const float* bih  = (const float*)d_in[4];
    const float* bhh  = (const float*)d_in[5];
    const float* Wk   = (const float*)d_in[6];
    const float* bk   = (const float*)d_in[7];
    const float* We   = (const float*)d_in[8];
    const float* be   = (const float*)d_in[9];
    const float* Wt   = (const float*)d_in[10];
    const float* bt   = (const float*)d_in[11];
    float* out = (float*)d_out;

    const int B = in_sizes[0] / T_LEN;   // 16384

    unsigned short* WhFhi = (unsigned short*)d_ws;        // 6*6*64*8 f16
    unsigned short* WhFlo = WhFhi + L * NT * 64 * 8;
    unsigned short* WiFhi = WhFlo + L * NT * 64 * 8;      // 5*6*64*8 f16

    const int nPack = (L * NT * 64) + ((L - 1) * NT * 64);  // 4224
    pack_frags<<<(nPack + 255) / 256, 256, 0, stream>>>(Whh, Wih, WhFhi, WhFlo, WiFhi);
    gru_mfma<<<B / BT, TPB, 0, stream>>>(x, Wih0, bih, bhh, WhFhi, WhFlo, WiFhi,
                                         Wk, bk, We, be, Wt, bt, out, B);
}

// Round 12
// 244.105 us; speedup vs baseline: 7.1448x; 7.1448x over previous
//
#include <hip/hip_runtime.h>

#define T_LEN 100
#define H 32
#define L 6
#define NT 6          // 96 gate rows / 16
#define TPB 512       // 8 waves: SIMD s hosts waves {s, s+4}
#define BT 32         // two independent 16-batch groups per block
#define NPAIR 25      // four timesteps per barrier interval
#define NK (NPAIR + L - 1)   // 30 intervals, layer skew d = layer
#define S1 1.44269504088896f   // log2(e)

typedef float f32x4  __attribute__((ext_vector_type(4)));
typedef _Float16 f16x8 __attribute__((ext_vector_type(8)));

union FragU { f16x8 h; f32x4 f; unsigned int u[4]; };

__device__ inline unsigned short f2h(float f) {
    union { _Float16 h; unsigned short u; } v; v.h = (_Float16)f; return v.u;
}
__device__ inline float rcpa(float x)  { return __builtin_amdgcn_rcpf(x); }
__device__ inline float exp2b(float x) { return __builtin_amdgcn_exp2f(x); }

// pack f32 pair -> one u32 of 2 f16 (RTZ)
__device__ inline unsigned int pk16(float a, float b) {
    unsigned int h;
    asm("v_cvt_pkrtz_f16_f32 %0, %1, %2" : "=v"(h) : "v"(a), "v"(b));
    return h;
}

// ---- prep: pack weight A-fragments as f16 (hi only -- matmul-operand
// quantization; the f32 recurrent state hp is never quantized), pre-scaled
// by -log2e / -2log2e, with kappa k-relabeling: hardware k-slot (gk*8+e)
// holds W column j = (e>>2)*16 + gk*4 + (e&3).  This makes MFMA C/D layout
// == B-frag layout.
__global__ void pack_frags(const float* __restrict__ Whh, const float* __restrict__ Wih,
                           unsigned short* __restrict__ WhFhi,
                           unsigned short* __restrict__ WiFhi)
{
    int tid = blockIdx.x * blockDim.x + threadIdx.x;
    const int NWH = L * NT * 64;          // 2304
    const int NWI = (L - 1) * NT * 64;    // 1920
    if (tid >= NWH + NWI) return;
    const float* src; unsigned short *dhi; int tile, lane;
    if (tid < NWH) {
        int l = tid / (NT * 64); int r = tid % (NT * 64); tile = r / 64; lane = r % 64;
        src = Whh + l * 96 * H;
        dhi = WhFhi + tid * 8;
    } else {
        int t2 = tid - NWH;
        int l = t2 / (NT * 64); int r = t2 % (NT * 64); tile = r / 64; lane = r % 64;
        src = Wih + l * 96 * H;           // W_ih[l] feeds layer l+1
        dhi = WiFhi + t2 * 8;
    }
    int row = tile * 16 + (lane & 15);
    int gk  = lane >> 4;
    float scale = (row < 64) ? -S1 : -2.0f * S1;
    unsigned short thi[8];
#pragma unroll
    for (int e = 0; e < 8; ++e) {
        int j = ((e >> 2) << 4) + (gk << 2) + (e & 3);   // kappa^-1
        thi[e] = f2h(scale * src[row * H + j]);
    }
    *(uint4*)dhi = *(const uint4*)thi;
}

// ---- main: 8-wave layer ladder, barrier-synced, four steps per interval,
// SINGLE-PRODUCT f16 matmuls everywhere: own-h = whh x h_f16, input =
// wih x handoff_f16.  The GRU memory path (z*h_prev) uses the exact f32
// hp state -- f16 only ever touches matmul operands (same error class as
// the R7 handoff change, which passed).
// VALU-balanced wave map: SIMD pairs {L0,L1a} {L2,L1b} {L3,L5a} {L4,L5b}.
__global__ __launch_bounds__(TPB, 2) void gru_mfma(
    const float* __restrict__ x,          // [B][T]
    const float* __restrict__ Wih0,       // [96]
    const float* __restrict__ bih,        // [6][96]
    const float* __restrict__ bhh,        // [6][96]
    const unsigned short* __restrict__ WhFhi,
    const unsigned short* __restrict__ WiFhi,
    const float* __restrict__ Wk, const float* __restrict__ bk,
    const float* __restrict__ We, const float* __restrict__ be,
    const float* __restrict__ Wt, const float* __restrict__ bt,
    float* __restrict__ out, int B)
{
    // handoff slot per (layer 0..4, interval parity, step 0..3), 2 KB each:
    // grp0{hi 1K} grp1{hi 1K}.  row b = 64B; logical 16B-block c stored at
    // column c ^ ((b>>1)&3).
    __shared__ unsigned char slot[5][2][4][2048];   // 80 KB
    __shared__ float xt[T_LEN][BT];
    __shared__ float hpart[L][3][BT];

    const int tid  = threadIdx.x;
    const int wv   = tid >> 6;        // wave index
    const int lane = tid & 63;
    const int b    = lane & 15;       // batch col (MFMA N)
    const int g    = lane >> 4;       // k-group
    const int b0   = blockIdx.x * BT;

    // wave -> (layer, group-mask).  SIMD pairs {w0,w4} {w1,w5} {w2,w6}
    // {w3,w7}; L1 and L5 split in half so every SIMD carries ~1.5 layers
    // of gate VALU/trans work:
    //   S0:{L0, L1.g0}  S1:{L2, L1.g1}  S2:{L3, L5.g0}  S3:{L4, L5.g1}
    int layer, grmask;
    switch (wv) {
      case 0: layer = 0; grmask = 3; break;   // light scalar-input layer
      case 4: layer = 1; grmask = 1; break;
      case 1: layer = 2; grmask = 3; break;
      case 5: layer = 1; grmask = 2; break;
      case 2: layer = 3; grmask = 3; break;
      case 6: layer = 5; grmask = 1; break;
      case 3: layer = 4; grmask = 3; break;
      default: layer = 5; grmask = 2; break;  // w7
    }

    // stage x tile
    for (int idx = tid; idx < T_LEN * BT; idx += TPB) {
        int bb = idx / T_LEN, t = idx % T_LEN;
        xt[t][bb] = x[(b0 + bb) * T_LEN + t];
    }

    // weight fragments for my layer, held in registers all 100 steps
    f16x8 whh[NT], wih[NT];
#pragma unroll
    for (int t6 = 0; t6 < NT; ++t6)
        whh[t6] = ((const f16x8*)WhFhi)[(layer * NT + t6) * 64 + lane];
    if (layer > 0) {
#pragma unroll
        for (int t6 = 0; t6 < NT; ++t6)
            wih[t6] = ((const f16x8*)WiFhi)[((layer - 1) * NT + t6) * 64 + lane];
    }

    // pre-scaled biases in C/D layout (row = t6*16 + g*4 + r)
    f32x4 bc[4], bxn[2], bhn[2];
    {
        const int rb = g * 4;
#pragma unroll
        for (int t6 = 0; t6 < 4; ++t6)
#pragma unroll
            for (int r = 0; r < 4; ++r) {
                int row = t6 * 16 + rb + r;
                bc[t6][r] = -S1 * (bih[layer * 96 + row] + bhh[layer * 96 + row]);
            }
#pragma unroll
        for (int tt = 0; tt < 2; ++tt)
#pragma unroll
            for (int r = 0; r < 4; ++r) {
                int row = 64 + tt * 16 + rb + r;
                bxn[tt][r] = -2.0f * S1 * bih[layer * 96 + row];
                bhn[tt][r] = -2.0f * S1 * bhh[layer * 96 + row];
            }
        if (layer == 0) {
            // layer-0 wave never uses wih as frags: reuse for pre-scaled f32
            // input weights via the union view
#pragma unroll
            for (int t6 = 0; t6 < NT; ++t6) {
                FragU u;
#pragma unroll
                for (int r = 0; r < 4; ++r) {
                    int row = t6 * 16 + rb + r;
                    float s = (row < 64) ? -S1 : -2.0f * S1;
                    u.f[r] = s * Wih0[row];
                }
                wih[t6] = u.h;
            }
        }
    }

    float hp[2][8];
#pragma unroll
    for (int gr = 0; gr < 2; ++gr)
#pragma unroll
        for (int i = 0; i < 8; ++i) hp[gr][i] = 0.0f;
    f16x8 hfH[2] = {{0,0,0,0,0,0,0,0},{0,0,0,0,0,0,0,0}};

    // unified slot offset (read & write identical): row b, logical block g,
    // XOR-swizzled by (b>>1)&3.  Group gr adds gr*1024.
    const int soff = b * 64 + ((g ^ ((b >> 1) & 3)) << 4);
    unsigned char* const sbase = (unsigned char*)slot;

    // one GRU step for BOTH batch groups.  rq = producer parity to read,
    // wp = parity to write, st = step slot (0..3).
    auto do_step2 = [&](int t, int rq, int wp, int st) {
        f32x4 acc[2][4], accX[2][2], accH[2][2];
        // both handoff LDS reads first; latency hides under own-h MFMAs
        f16x8 iH[2];
        if (layer > 0) {
            const unsigned char* ru = sbase + (((layer - 1) * 8 + rq * 4 + st) << 11);
            if (grmask & 1) iH[0] = *(const f16x8*)(ru + soff);
            if (grmask & 2) iH[1] = *(const f16x8*)(ru + 1024 + soff);
        }
        // ---- MFMA phase: single product own-h (C-init = biases) ----
#pragma unroll
        for (int gr = 0; gr < 2; ++gr)
            if (grmask & (1 << gr)) {
#pragma unroll
                for (int t6 = 0; t6 < 4; ++t6)
                    acc[gr][t6] = __builtin_amdgcn_mfma_f32_16x16x32_f16(whh[t6], hfH[gr], bc[t6], 0, 0, 0);
#pragma unroll
                for (int tt = 0; tt < 2; ++tt)
                    accH[gr][tt] = __builtin_amdgcn_mfma_f32_16x16x32_f16(whh[4 + tt], hfH[gr], bhn[tt], 0, 0, 0);
            }
        // input product: wih x iH (hi-only handoff) / scalar x for layer 0
        if (layer == 0) {
#pragma unroll
            for (int gr = 0; gr < 2; ++gr)
                if (grmask & (1 << gr)) {
                    float xv = xt[t][gr * 16 + b];
#pragma unroll
                    for (int t6 = 0; t6 < 4; ++t6) {
                        FragU u; u.h = wih[t6];
#pragma unroll
                        for (int r = 0; r < 4; ++r)
                            acc[gr][t6][r] = fmaf(u.f[r], xv, acc[gr][t6][r]);
                    }
#pragma unroll
                    for (int tt = 0; tt < 2; ++tt) {
                        FragU u; u.h = wih[4 + tt];
#pragma unroll
                        for (int r = 0; r < 4; ++r)
                            accX[gr][tt][r] = fmaf(u.f[r], xv, bxn[tt][r]);
                    }
                }
        } else {
#pragma unroll
            for (int gr = 0; gr < 2; ++gr)
                if (grmask & (1 << gr)) {
#pragma unroll
                    for (int t6 = 0; t6 < 4; ++t6)
                        acc[gr][t6] = __builtin_amdgcn_mfma_f32_16x16x32_f16(wih[t6], iH[gr], acc[gr][t6], 0, 0, 0);
#pragma unroll
                    for (int tt = 0; tt < 2; ++tt)
                        accX[gr][tt] = __builtin_amdgcn_mfma_f32_16x16x32_f16(wih[4 + tt], iH[gr], bxn[tt], 0, 0, 0);
                }
        }
        // ---- gate phase: both groups together (16 independent chains) ----
        // gates (pre-scaled): Er=e^-rpre, Ez=e^-zpre, En=e^-2npre
        // r = 1/(1+Er); n = (1-En)/(1+En); h = [n*Ez + hp] / (1+Ez)
#pragma unroll
        for (int gr = 0; gr < 2; ++gr)
            if (grmask & (1 << gr)) {
#pragma unroll
                for (int jj = 0; jj < 2; ++jj)
#pragma unroll
                    for (int r = 0; r < 4; ++r) {
                        float Er = exp2b(acc[gr][jj][r]);
                        float Ez = exp2b(acc[gr][2 + jj][r]);
                        float rg = rcpa(1.0f + Er);
                        float u  = fmaf(rg, accH[gr][jj][r], accX[gr][jj][r]);
                        float En = exp2b(u);
                        float en1 = 1.0f + En, ez1 = 1.0f + Ez;
                        float d   = rcpa(en1 * ez1);
                        float num = fmaf(hp[gr][jj * 4 + r], en1, (1.0f - En) * Ez);
                        hp[gr][jj * 4 + r] = num * d;
                    }
            }
        // ---- pack + handoff write, both groups (hi only, no residual) ----
#pragma unroll
        for (int gr = 0; gr < 2; ++gr)
            if (grmask & (1 << gr)) {
                unsigned int h01 = pk16(hp[gr][0], hp[gr][1]);
                unsigned int h23 = pk16(hp[gr][2], hp[gr][3]);
                unsigned int h45 = pk16(hp[gr][4], hp[gr][5]);
                unsigned int h67 = pk16(hp[gr][6], hp[gr][7]);
                FragU Hu;
                Hu.u[0] = h01; Hu.u[1] = h23; Hu.u[2] = h45; Hu.u[3] = h67;
                hfH[gr] = Hu.h;
                if (layer < L - 1) {
                    unsigned char* wp8 = sbase + ((layer * 8 + wp * 4 + st) << 11) + gr * 1024;
                    *(uint4*)(wp8 + soff) = make_uint4(h01, h23, h45, h67);
                }
            }
    };

    __syncthreads();

    for (int i = 0; i < NK; ++i) {
        int k = i - layer;            // local 4-step chunk index
        if (0 <= k && k < NPAIR) {
            const int p = i & 1, q = p ^ 1;
#pragma unroll
            for (int st = 0; st < 4; ++st)
                do_step2(4 * k + st, q, p, st);
        }
        __syncthreads();
    }

    // heads: per-(layer,group) partial over 32 hidden units, then cross-wave reduce
    {
        const int rb = g * 4;
#pragma unroll
        for (int hd = 0; hd < 3; ++hd) {
            const float* W = (hd == 0) ? Wk : (hd == 1) ? We : Wt;
#pragma unroll
            for (int gr = 0; gr < 2; ++gr)
                if (grmask & (1 << gr)) {
                    float s = 0.0f;
#pragma unroll
                    for (int jj = 0; jj < 2; ++jj)
#pragma unroll
                        for (int r = 0; r < 4; ++r)
                            s = fmaf(W[layer * H + jj * 16 + rb + r], hp[gr][jj * 4 + r], s);
                    s += __shfl_xor(s, 16, 64);
                    s += __shfl_xor(s, 32, 64);
                    if (g == 0) hpart[layer][hd][gr * 16 + b] = s;
                }
        }
        __syncthreads();
        if (wv < 3 && lane < BT) {
            int bb = lane;
            float s = (wv == 0) ? bk[0] : (wv == 1) ? be[0] : bt[0];
#pragma unroll
            for (int l = 0; l < L; ++l) s += hpart[l][wv][bb];
            out[wv * B + b0 + bb] = s;
        }
    }
}

extern "C" void kernel_launch(void* const* d_in, const int* in_sizes, int n_in,
                              void* d_out, int out_size, void* d_ws, size_t ws_size,
                              hipStream_t stream)
{
    const float* x    = (const float*)d_in[0];
    const float* Wih0 = (const float*)d_in[1];
    const float* Wih  = (const float*)d_in[2];
    const float* Whh  = (const float*)d_in[3];
    const float* bih  = (const float*)d_in[4];
    const float* bhh  = (const float*)d_in[5];
    const float* Wk   = (const float*)d_in[6];
    const float* bk   = (const float*)d_in[7];
    const float* We   = (const float*)d_in[8];
    const float* be   = (const float*)d_in[9];
    const float* Wt   = (const float*)d_in[10];
    const float* bt   = (const float*)d_in[11];
    float* out = (float*)d_out;

    const int B = in_sizes[0] / T_LEN;   // 16384

    unsigned short* WhFhi = (unsigned short*)d_ws;        // 6*6*64*8 f16
    unsigned short* WiFhi = WhFhi + L * NT * 64 * 8;      // 5*6*64*8 f16

    const int nPack = (L * NT * 64) + ((L - 1) * NT * 64);  // 4224
    pack_frags<<<(nPack + 255) / 256, 256, 0, stream>>>(Whh, Wih, WhFhi, WiFhi);
    gru_mfma<<<B / BT, TPB, 0, stream>>>(x, Wih0, bih, bhh, WhFhi, WiFhi,
                                         Wk, bk, We, be, Wt, bt, out, B);
}